// Round 4
// baseline (780.496 us; speedup 1.0000x reference)
//
#include <hip/hip_runtime.h>
#include <math.h>

#define NPTS 32768
#define DD 8
#define OO 20      // ORDER+1
#define PP 20
#define NCHAIN 7   // c=0: mean chain; c=1..6: variance moment k=c
#define NT 2       // point-tiles (32 pts each) per wave — amortizes A loads

typedef _Float16 half8 __attribute__((ext_vector_type(8)));
typedef __fp16 fp16x2 __attribute__((ext_vector_type(2)));
typedef float floatx16 __attribute__((ext_vector_type(16)));
typedef unsigned uint4v __attribute__((ext_vector_type(4)));
typedef unsigned int u32;

#define AS1 __attribute__((address_space(1)))
#define AS3 __attribute__((address_space(3)))

// sigma: row permutation baked into A so that C-layout output == next B layout
// (swap rows 4..7 <-> 8..11; identity elsewhere)
__device__ __forceinline__ int sigma_row(int m) {
    return (m >= 4 && m < 12) ? (m ^ 12) : m;
}

// basis b_q = binom[q] t^q (1-t)^(19-q), fp32 (prep only)
__device__ __forceinline__ void basis20(float tv, float* g) {
    constexpr float binom[OO] = {
        1.f, 19.f, 171.f, 969.f, 3876.f, 11628.f, 27132.f, 50388.f, 75582.f,
        92378.f, 92378.f, 75582.f, 50388.f, 27132.f, 11628.f, 3876.f, 969.f,
        171.f, 19.f, 1.f};
    float a = tv, b = 1.f - tv, v = 1.f;
#pragma unroll
    for (int q = 0; q < OO; ++q) { g[q] = v; v *= a; }
    v = 1.f;
#pragma unroll
    for (int q = OO - 1; q >= 0; --q) { g[q] = g[q] * v * binom[q]; v *= b; }
}

// RTN pack of two f32 into f16x2 dword (prep only — accuracy over speed)
__device__ __forceinline__ unsigned pk2rtn(float a, float b) {
    union { _Float16 h[2]; unsigned u; } cv;
    cv.h[0] = (_Float16)a; cv.h[1] = (_Float16)b;
    return cv.u;
}

__device__ __forceinline__ unsigned pack_pk(float x, float y) {
    union { fp16x2 h; unsigned u; } cv;
    cv.h = __builtin_amdgcn_cvt_pkrtz(x, y);
    return cv.u;
}

__device__ __forceinline__ fp16x2 u2h(unsigned u) {
    union { unsigned u; fp16x2 h; } c; c.u = u; return c.h;
}
__device__ __forceinline__ unsigned h2u(fp16x2 h) {
    union { unsigned u; fp16x2 h; } c; c.h = h; return c.u;
}

// ---------------------------------------------------------------------------
// Prep (one launch, three ranges):
//   W0[c][p][q]  fp32 = c==0 ? exp(meanw0) : exp(2*meanw0 + c*varw0)
//   WA[c][i][p][frag][lane][j] f16 — MFMA A-fragment order:
//     element = Apad[m][k], m = lane&31, k = (lane>>5)*8 + frag*16 + j,
//     Apad[m][k] = (q=sigma(m))<20 && k<20 ? W_c[o=k][q] : 0
//     This makes global_load_lds's linear (lane*16B) LDS write == the exact
//     per-lane ds_read_b128 fragment layout (conflict-free, no swizzle).
//   G[d][n]: 24 dwords (96B) of f16x2 gate records in per-lane layout:
//     dwords  0..5  lo-half gate  pairs: (g0,g1)(g2,g3)(g4,g5)(g6,g7)(g16,g17)(g18,g19)
//     dwords  6..11 lo-half gate² (squared in f32, rounded once)
//     dwords 12..17 hi-half gate  pairs: (g8,g9)..(g14,g15),(0,0),(0,0)
//     dwords 18..23 hi-half gate²
// ---------------------------------------------------------------------------
__global__ void prep_kernel(const float* __restrict__ X,
                            const float* __restrict__ meanw0,
                            const float* __restrict__ meanw,
                            const float* __restrict__ varw0,
                            const float* __restrict__ varw,
                            float* __restrict__ W0,
                            _Float16* __restrict__ WA,
                            unsigned* __restrict__ G) {
    int e = blockIdx.x * 256 + threadIdx.x;
    const int n0 = NCHAIN * PP * OO;                 // 2800
    const int nW = NCHAIN * (DD - 1) * PP * 32 * 32; // 1,003,520
    const int nG = NPTS * DD;                        // 262,144
    if (e < n0) {
        int q = e % OO;
        int rem = e / OO;
        int p = rem % PP;
        int c = rem / PP;
        float m = meanw0[p * OO + q];
        W0[e] = (c == 0) ? __expf(m) : __expf(2.f * m + (float)c * varw0[p * OO + q]);
    } else if (e < n0 + nW) {
        int idx = e - n0;
        int j = idx & 7; idx >>= 3;
        int l = idx & 63; idx >>= 6;
        int f = idx & 1; idx >>= 1;
        int p = idx % PP; idx /= PP;
        int i = idx % (DD - 1);
        int c = idx / (DD - 1);
        int m = l & 31;
        int k = (l >> 5) * 8 + f * 16 + j;
        int q = sigma_row(m);
        float v = 0.f;
        if (q < OO && k < OO) {
            int mi = ((i * PP + p) * OO + k) * OO + q;   // meanw[i][p][o=k][q']
            float mm = meanw[mi];
            v = (c == 0) ? __expf(mm) : __expf(2.f * mm + (float)c * varw[mi]);
        }
        WA[e - n0] = (_Float16)v;
    } else if (e < n0 + nW + nG) {
        int idx = e - n0 - nW;
        int n = idx & (NPTS - 1);
        int d = idx >> 15;
        float g[OO];
        basis20(X[(size_t)n * DD + d], g);
        float lo[12], hi12[12];
#pragma unroll
        for (int r = 0; r < 8; ++r) lo[r] = g[r];
#pragma unroll
        for (int r = 0; r < 4; ++r) lo[8 + r] = g[16 + r];
#pragma unroll
        for (int r = 0; r < 8; ++r) hi12[r] = g[8 + r];
#pragma unroll
        for (int r = 0; r < 4; ++r) hi12[8 + r] = 0.f;
        unsigned rec[24];
#pragma unroll
        for (int q = 0; q < 6; ++q) {
            rec[q]      = pk2rtn(lo[2 * q], lo[2 * q + 1]);
            rec[6 + q]  = pk2rtn(lo[2 * q] * lo[2 * q], lo[2 * q + 1] * lo[2 * q + 1]);
            rec[12 + q] = pk2rtn(hi12[2 * q], hi12[2 * q + 1]);
            rec[18 + q] = pk2rtn(hi12[2 * q] * hi12[2 * q], hi12[2 * q + 1] * hi12[2 * q + 1]);
        }
        uint4* out = (uint4*)(G + (size_t)(d * NPTS + n) * 24);
#pragma unroll
        for (int q = 0; q < 6; ++q) out[q] = ((const uint4*)rec)[q];
    }
}

// ---------------------------------------------------------------------------
// One wave = one p x NT*32 points x all 7 chains. Persistent state per
// (tile,c): stB0 (uint32x4 vector, IS the MFMA B0 operand — gate+pack writes
// in place, no marshal) + s45 (2 dwords for B1's real half; B1 tail dwords
// multiply zero-padded A columns k>=20, so they carry don't-care uz).
// A-matrices (14KB per i-step, shared by all 4 waves: same p) are staged
// block-wide into double-buffered LDS via global_load_lds, one step ahead;
// the hot loop reads them with conflict-free ds_read_b128 at lane*16.
// ---------------------------------------------------------------------------
__global__ __launch_bounds__(256, 4) void chain_kernel(
    const int* __restrict__ perm,
    const float* __restrict__ W0, const _Float16* __restrict__ WA,
    const unsigned* __restrict__ G, float* __restrict__ partial) {
    const int lane = threadIdx.x & 63;
    const int wv = threadIdx.x >> 6;
    const int nl = lane & 31;
    const bool hi = (lane >> 5) != 0;
    const int n0 = (blockIdx.x * 4 + wv) * (32 * NT);
    const int p = blockIdx.y;
    const int goff = hi ? 12 : 0;

    // [buf][c*1024 + frag*512 + lane*8] halves; 2 x 14336 B
    __shared__ __align__(16) _Float16 Alds[2][NCHAIN * 1024];

    int dp[DD];
#pragma unroll
    for (int i = 0; i < DD; ++i) dp[i] = perm[p * DD + i];

    // opaque zero: perm values are 0..7, so uz == 0, but the compiler can't
    // prove it — kZero stays pinned instead of being re-emitted per MFMA.
    const unsigned uz = ((unsigned)dp[0]) >> 20;
    const float fz = __uint_as_float(uz);
    floatx16 kZero;
#pragma unroll
    for (int r = 0; r < 16; ++r) kZero[r] = fz;

    // ---- issue staging of i=1 A-matrices into buf0 (latency hidden by init)
    {
        const _Float16* wbase = WA + (size_t)p * 1024;  // [c][i=0][p]
#pragma unroll
        for (int u = wv; u < 2 * NCHAIN; u += 4) {
            int c = u >> 1, h = u & 1;
            const _Float16* src =
                wbase + (size_t)c * (DD - 1) * PP * 1024 + h * 512 + lane * 8;
            __builtin_amdgcn_global_load_lds(
                (const AS1 u32*)src, (AS3 u32*)&Alds[0][u * 512], 16, 0, 0);
        }
    }

    uint4v   stB0[NT][NCHAIN];      // persistent B0 operand (in-place updates)
    unsigned s45[NT][NCHAIN][2];    // B1's two real dwords

    // ---- init: f0[k] = W0[c][p][k] * gate0[k] (f32, unpacked f16 gates) ----
#pragma unroll
    for (int tile = 0; tile < NT; ++tile) {
        const uint4* rp = (const uint4*)(
            G + ((size_t)dp[0] * NPTS + (n0 + tile * 32 + nl)) * 24 + goff);
        uint4 r0 = rp[0], r1 = rp[1], r2 = rp[2];
        unsigned gw[6] = {r0.x, r0.y, r0.z, r0.w, r1.x, r1.y};
        unsigned sw[6] = {r1.z, r1.w, r2.x, r2.y, r2.z, r2.w};
        float gcf[12], scf[12];
#pragma unroll
        for (int q = 0; q < 6; ++q) {
            fp16x2 gh = u2h(gw[q]), sh = u2h(sw[q]);
            gcf[2 * q] = (float)gh.x; gcf[2 * q + 1] = (float)gh.y;
            scf[2 * q] = (float)sh.x; scf[2 * q + 1] = (float)sh.y;
        }
#pragma unroll
        for (int c = 0; c < NCHAIN; ++c) {
            const float* w0r = W0 + (c * PP + p) * OO;
            float val[12];
#pragma unroll
            for (int r = 0; r < 8; ++r) {
                float ws = hi ? w0r[r + 8] : w0r[r];
                val[r] = ws * (c == 0 ? gcf[r] : scf[r]);
            }
#pragma unroll
            for (int r = 8; r < 12; ++r) {
                float ws = hi ? 0.f : w0r[r + 8];
                val[r] = ws * (c == 0 ? gcf[r] : scf[r]);
            }
#pragma unroll
            for (int e = 0; e < 4; ++e)
                stB0[tile][c][e] = pack_pk(val[2 * e], val[2 * e + 1]);
            s45[tile][c][0] = pack_pk(val[8], val[9]);
            s45[tile][c][1] = pack_pk(val[10], val[11]);
        }
    }

    const float coef[NCHAIN] = {0.f, 1.f, 0.5f, 1.f / 6.f, 1.f / 24.f,
                                1.f / 120.f, 1.f / 720.f};
    float sm[NT], sv[NT];
#pragma unroll
    for (int tile = 0; tile < NT; ++tile) { sm[tile] = 0.f; sv[tile] = 0.f; }

    __syncthreads();   // drains vmcnt → buf0 staged

#pragma unroll
    for (int i = 1; i < DD; ++i) {
        const int cur = (i - 1) & 1;

        // gate loads first (consumed soonest)
        uint4 gr[NT][3];
#pragma unroll
        for (int tile = 0; tile < NT; ++tile) {
            const uint4* rp = (const uint4*)(
                G + ((size_t)dp[i] * NPTS + (n0 + tile * 32 + nl)) * 24 + goff);
            gr[tile][0] = rp[0]; gr[tile][1] = rp[1]; gr[tile][2] = rp[2];
        }

        // issue next step's staging into the other buffer (latency hides
        // under this step's compute; drained by the end-of-step barrier)
        if (i < DD - 1) {
            const _Float16* wbase = WA + (size_t)(i * PP + p) * 1024;  // [c][i][p]
#pragma unroll
            for (int u = wv; u < 2 * NCHAIN; u += 4) {
                int c = u >> 1, h = u & 1;
                const _Float16* src =
                    wbase + (size_t)c * (DD - 1) * PP * 1024 + h * 512 + lane * 8;
                __builtin_amdgcn_global_load_lds(
                    (const AS1 u32*)src, (AS3 u32*)&Alds[cur ^ 1][u * 512], 16, 0, 0);
            }
        }

        unsigned gw[NT][6], sw[NT][6];
#pragma unroll
        for (int tile = 0; tile < NT; ++tile) {
            gw[tile][0] = gr[tile][0].x; gw[tile][1] = gr[tile][0].y;
            gw[tile][2] = gr[tile][0].z; gw[tile][3] = gr[tile][0].w;
            gw[tile][4] = gr[tile][1].x; gw[tile][5] = gr[tile][1].y;
            sw[tile][0] = gr[tile][1].z; sw[tile][1] = gr[tile][1].w;
            sw[tile][2] = gr[tile][2].x; sw[tile][3] = gr[tile][2].y;
            sw[tile][4] = gr[tile][2].z; sw[tile][5] = gr[tile][2].w;
        }

        // final step needs f32 gates for the accurate reduction
        float gcf[NT][12], scf[NT][12];
        if (i == DD - 1) {
#pragma unroll
            for (int tile = 0; tile < NT; ++tile)
#pragma unroll
                for (int q = 0; q < 6; ++q) {
                    fp16x2 gh = u2h(gw[tile][q]), sh = u2h(sw[tile][q]);
                    gcf[tile][2 * q] = (float)gh.x; gcf[tile][2 * q + 1] = (float)gh.y;
                    scf[tile][2 * q] = (float)sh.x; scf[tile][2 * q + 1] = (float)sh.y;
                }
        }

#pragma unroll
        for (int c = 0; c < NCHAIN; ++c) {
            // conflict-free fragment reads: lane*16B contiguous
            const _Float16* ab = &Alds[cur][c * 1024 + lane * 8];
            half8 A0 = *(const half8*)(ab);
            half8 A1 = *(const half8*)(ab + 512);

#pragma unroll
            for (int tile = 0; tile < NT; ++tile) {
                union { uint4v u; half8 h; } B0;
                B0.u = stB0[tile][c];
                union { unsigned u[4]; half8 h; } B1;
                B1.u[0] = s45[tile][c][0]; B1.u[1] = s45[tile][c][1];
                B1.u[2] = uz;              B1.u[3] = uz;  // k>=20: A cols are 0

                floatx16 acc;
                acc = __builtin_amdgcn_mfma_f32_32x32x16_f16(A0, B0.h, kZero, 0, 0, 0);
                acc = __builtin_amdgcn_mfma_f32_32x32x16_f16(A1, B1.h, acc, 0, 0, 0);

                if (i < DD - 1) {
                    // gate+pack in f16, written IN PLACE into the B0/B1 state
#pragma unroll
                    for (int e = 0; e < 4; ++e) {
                        fp16x2 pr = __builtin_amdgcn_cvt_pkrtz(acc[2 * e], acc[2 * e + 1]);
                        fp16x2 gv = u2h(c == 0 ? gw[tile][e] : sw[tile][e]);
                        stB0[tile][c][e] = h2u(pr * gv);
                    }
#pragma unroll
                    for (int e = 4; e < 6; ++e) {
                        fp16x2 pr = __builtin_amdgcn_cvt_pkrtz(acc[2 * e], acc[2 * e + 1]);
                        fp16x2 gv = u2h(c == 0 ? gw[tile][e] : sw[tile][e]);
                        s45[tile][c][e - 4] = h2u(pr * gv);
                    }
                } else {
                    float s = 0.f;
#pragma unroll
                    for (int r = 0; r < 12; ++r)
                        s += acc[r] * (c == 0 ? gcf[tile][r] : scf[tile][r]);
                    if (c == 0) sm[tile] = s;
                    else        sv[tile] += coef[c] * s;
                }
            }
        }

        if (i < DD - 1) __syncthreads();  // staging done + all ds_reads done
    }

    // ---- epilogue: combine half-waves, write per-p partials ----
#pragma unroll
    for (int tile = 0; tile < NT; ++tile) {
        float m = sm[tile] + __shfl_xor(sm[tile], 32, 64);
        float v = sv[tile] + __shfl_xor(sv[tile], 32, 64);
        if (lane < 32) {
            partial[(size_t)p * NPTS + n0 + tile * 32 + nl] = m;
            partial[(size_t)(PP + p) * NPTS + n0 + tile * 32 + nl] = v;
        }
    }
}

// ---------------------------------------------------------------------------
// Reduce over p: out[n][0] = sum_p mean_p[n]; out[n][1] = sum_p var_p[n]
// ---------------------------------------------------------------------------
__global__ void reduce_kernel(const float* __restrict__ partial,
                              float* __restrict__ out) {
    int n = blockIdx.x * 256 + threadIdx.x;
    float m = 0.f, v = 0.f;
#pragma unroll
    for (int p = 0; p < PP; ++p) {
        m += partial[(size_t)p * NPTS + n];
        v += partial[(size_t)(PP + p) * NPTS + n];
    }
    out[2 * n] = m;
    out[2 * n + 1] = v;
}

extern "C" void kernel_launch(void* const* d_in, const int* in_sizes, int n_in,
                              void* d_out, int out_size, void* d_ws, size_t ws_size,
                              hipStream_t stream) {
    const float* X      = (const float*)d_in[0];
    const int*   perm   = (const int*)d_in[1];
    const float* meanw0 = (const float*)d_in[2];
    const float* meanw  = (const float*)d_in[3];
    const float* varw0  = (const float*)d_in[4];
    const float* varw   = (const float*)d_in[5];
    float* out = (float*)d_out;

    // workspace: [W0: 2800 f32 = 11,200B][WA: 1,003,520 f16 = 2,007,040B]
    //            [partial: 2*20*32768 f32 = 5,242,880B]
    //            [G: 8*32768*24 dwords = 25,165,824B]   total 32,426,944B
    float*     W0      = (float*)d_ws;
    _Float16*  WA      = (_Float16*)((char*)d_ws + 11200);
    float*     partial = (float*)((char*)d_ws + 11200 + 2007040);
    unsigned*  G       = (unsigned*)((char*)d_ws + 11200 + 2007040 + 5242880);

    int prep_n = NCHAIN * PP * OO + NCHAIN * (DD - 1) * PP * 32 * 32 + NPTS * DD;
    hipLaunchKernelGGL(prep_kernel, dim3((prep_n + 255) / 256), dim3(256), 0,
                       stream, X, meanw0, meanw, varw0, varw, W0, WA, G);

    dim3 grid(NPTS / (128 * NT), PP);  // 4 waves/block, NT*32 pts/wave
    hipLaunchKernelGGL(chain_kernel, grid, dim3(256), 0, stream,
                       perm, W0, WA, G, partial);

    hipLaunchKernelGGL(reduce_kernel, dim3(NPTS / 256), dim3(256), 0, stream,
                       partial, out);
}

// Round 5
// 163.179 us; speedup vs baseline: 4.7831x; 4.7831x over previous
//
#include <hip/hip_runtime.h>
#include <math.h>

#define NPTS 32768
#define DD 8
#define OO 20      // ORDER+1
#define PP 20
#define NCHAIN 7   // c=0: mean chain; c=1..6: variance moment k=c
#define NT 2       // point-tiles (32 pts each) per wave — amortizes A loads

typedef _Float16 half8 __attribute__((ext_vector_type(8)));
typedef __fp16 fp16x2 __attribute__((ext_vector_type(2)));
typedef float floatx16 __attribute__((ext_vector_type(16)));
typedef unsigned uint4v __attribute__((ext_vector_type(4)));
typedef unsigned int u32;

#define AS1 __attribute__((address_space(1)))
#define AS3 __attribute__((address_space(3)))

// sigma: row permutation baked into A so that C-layout output == next B layout
// (swap rows 4..7 <-> 8..11; identity elsewhere)
__device__ __forceinline__ int sigma_row(int m) {
    return (m >= 4 && m < 12) ? (m ^ 12) : m;
}

// basis b_q = binom[q] t^q (1-t)^(19-q), fp32 (prep only)
__device__ __forceinline__ void basis20(float tv, float* g) {
    constexpr float binom[OO] = {
        1.f, 19.f, 171.f, 969.f, 3876.f, 11628.f, 27132.f, 50388.f, 75582.f,
        92378.f, 92378.f, 75582.f, 50388.f, 27132.f, 11628.f, 3876.f, 969.f,
        171.f, 19.f, 1.f};
    float a = tv, b = 1.f - tv, v = 1.f;
#pragma unroll
    for (int q = 0; q < OO; ++q) { g[q] = v; v *= a; }
    v = 1.f;
#pragma unroll
    for (int q = OO - 1; q >= 0; --q) { g[q] = g[q] * v * binom[q]; v *= b; }
}

// RTN pack of two f32 into f16x2 dword (prep only — accuracy over speed)
__device__ __forceinline__ unsigned pk2rtn(float a, float b) {
    union { _Float16 h[2]; unsigned u; } cv;
    cv.h[0] = (_Float16)a; cv.h[1] = (_Float16)b;
    return cv.u;
}

__device__ __forceinline__ unsigned pack_pk(float x, float y) {
    union { fp16x2 h; unsigned u; } cv;
    cv.h = __builtin_amdgcn_cvt_pkrtz(x, y);
    return cv.u;
}

__device__ __forceinline__ fp16x2 u2h(unsigned u) {
    union { unsigned u; fp16x2 h; } c; c.u = u; return c.h;
}
__device__ __forceinline__ unsigned h2u(fp16x2 h) {
    union { unsigned u; fp16x2 h; } c; c.h = h; return c.u;
}

// ---------------------------------------------------------------------------
// Prep (one launch, three ranges):
//   W0[c][p][q]  fp32 = c==0 ? exp(meanw0) : exp(2*meanw0 + c*varw0)
//   WA[c][i][p][frag][lane][j] f16 — MFMA A-fragment order:
//     element = Apad[m][k], m = lane&31, k = (lane>>5)*8 + frag*16 + j,
//     Apad[m][k] = (q=sigma(m))<20 && k<20 ? W_c[o=k][q] : 0
//     This makes global_load_lds's linear (lane*16B) LDS write == the exact
//     per-lane ds_read_b128 fragment layout (conflict-free, no swizzle).
//   G[d][n]: 24 dwords (96B) of f16x2 gate records in per-lane layout:
//     dwords  0..5  lo-half gate  pairs: (g0,g1)(g2,g3)(g4,g5)(g6,g7)(g16,g17)(g18,g19)
//     dwords  6..11 lo-half gate² (squared in f32, rounded once)
//     dwords 12..17 hi-half gate  pairs: (g8,g9)..(g14,g15),(0,0),(0,0)
//     dwords 18..23 hi-half gate²
// ---------------------------------------------------------------------------
__global__ void prep_kernel(const float* __restrict__ X,
                            const float* __restrict__ meanw0,
                            const float* __restrict__ meanw,
                            const float* __restrict__ varw0,
                            const float* __restrict__ varw,
                            float* __restrict__ W0,
                            _Float16* __restrict__ WA,
                            unsigned* __restrict__ G) {
    int e = blockIdx.x * 256 + threadIdx.x;
    const int n0 = NCHAIN * PP * OO;                 // 2800
    const int nW = NCHAIN * (DD - 1) * PP * 32 * 32; // 1,003,520
    const int nG = NPTS * DD;                        // 262,144
    if (e < n0) {
        int q = e % OO;
        int rem = e / OO;
        int p = rem % PP;
        int c = rem / PP;
        float m = meanw0[p * OO + q];
        W0[e] = (c == 0) ? __expf(m) : __expf(2.f * m + (float)c * varw0[p * OO + q]);
    } else if (e < n0 + nW) {
        int idx = e - n0;
        int j = idx & 7; idx >>= 3;
        int l = idx & 63; idx >>= 6;
        int f = idx & 1; idx >>= 1;
        int p = idx % PP; idx /= PP;
        int i = idx % (DD - 1);
        int c = idx / (DD - 1);
        int m = l & 31;
        int k = (l >> 5) * 8 + f * 16 + j;
        int q = sigma_row(m);
        float v = 0.f;
        if (q < OO && k < OO) {
            int mi = ((i * PP + p) * OO + k) * OO + q;   // meanw[i][p][o=k][q']
            float mm = meanw[mi];
            v = (c == 0) ? __expf(mm) : __expf(2.f * mm + (float)c * varw[mi]);
        }
        WA[e - n0] = (_Float16)v;
    } else if (e < n0 + nW + nG) {
        int idx = e - n0 - nW;
        int n = idx & (NPTS - 1);
        int d = idx >> 15;
        float g[OO];
        basis20(X[(size_t)n * DD + d], g);
        float lo[12], hi12[12];
#pragma unroll
        for (int r = 0; r < 8; ++r) lo[r] = g[r];
#pragma unroll
        for (int r = 0; r < 4; ++r) lo[8 + r] = g[16 + r];
#pragma unroll
        for (int r = 0; r < 8; ++r) hi12[r] = g[8 + r];
#pragma unroll
        for (int r = 0; r < 4; ++r) hi12[8 + r] = 0.f;
        unsigned rec[24];
#pragma unroll
        for (int q = 0; q < 6; ++q) {
            rec[q]      = pk2rtn(lo[2 * q], lo[2 * q + 1]);
            rec[6 + q]  = pk2rtn(lo[2 * q] * lo[2 * q], lo[2 * q + 1] * lo[2 * q + 1]);
            rec[12 + q] = pk2rtn(hi12[2 * q], hi12[2 * q + 1]);
            rec[18 + q] = pk2rtn(hi12[2 * q] * hi12[2 * q], hi12[2 * q + 1] * hi12[2 * q + 1]);
        }
        uint4* out = (uint4*)(G + (size_t)(d * NPTS + n) * 24);
#pragma unroll
        for (int q = 0; q < 6; ++q) out[q] = ((const uint4*)rec)[q];
    }
}

// ---------------------------------------------------------------------------
// One wave = one p x NT*32 points x all 7 chains. Persistent state per
// (tile,c): stB0 (uint32x4 vector, IS the MFMA B0 operand — gate+pack writes
// in place, no marshal) + s45 (2 dwords for B1's real half; B1 tail dwords
// multiply zero-padded A columns k>=20, so they carry don't-care uz).
// A-matrices (14KB per i-step, shared by all 4 waves: same p) are staged
// block-wide into double-buffered LDS via global_load_lds, one step ahead;
// the hot loop reads them with conflict-free ds_read_b128 at lane*16.
// NOTE: live state needs ~120 VGPRs — do NOT raise the min-waves/EU arg of
// __launch_bounds__ above 2: (256,4) capped the allocator at 64 VGPRs and
// spilled everything to scratch (1.67 GB of scratch traffic, 8x slower).
// ---------------------------------------------------------------------------
__global__ __launch_bounds__(256, 2) void chain_kernel(
    const int* __restrict__ perm,
    const float* __restrict__ W0, const _Float16* __restrict__ WA,
    const unsigned* __restrict__ G, float* __restrict__ partial) {
    const int lane = threadIdx.x & 63;
    const int wv = threadIdx.x >> 6;
    const int nl = lane & 31;
    const bool hi = (lane >> 5) != 0;
    const int n0 = (blockIdx.x * 4 + wv) * (32 * NT);
    const int p = blockIdx.y;
    const int goff = hi ? 12 : 0;

    // [buf][c*1024 + frag*512 + lane*8] halves; 2 x 14336 B
    __shared__ __align__(16) _Float16 Alds[2][NCHAIN * 1024];

    int dp[DD];
#pragma unroll
    for (int i = 0; i < DD; ++i) dp[i] = perm[p * DD + i];

    // opaque zero: perm values are 0..7, so uz == 0, but the compiler can't
    // prove it — kZero stays pinned instead of being re-emitted per MFMA.
    const unsigned uz = ((unsigned)dp[0]) >> 20;
    const float fz = __uint_as_float(uz);
    floatx16 kZero;
#pragma unroll
    for (int r = 0; r < 16; ++r) kZero[r] = fz;

    // ---- issue staging of i=1 A-matrices into buf0 (latency hidden by init)
    {
        const _Float16* wbase = WA + (size_t)p * 1024;  // [c][i=0][p]
#pragma unroll
        for (int u = wv; u < 2 * NCHAIN; u += 4) {
            int c = u >> 1, h = u & 1;
            const _Float16* src =
                wbase + (size_t)c * (DD - 1) * PP * 1024 + h * 512 + lane * 8;
            __builtin_amdgcn_global_load_lds(
                (const AS1 u32*)src, (AS3 u32*)&Alds[0][u * 512], 16, 0, 0);
        }
    }

    uint4v   stB0[NT][NCHAIN];      // persistent B0 operand (in-place updates)
    unsigned s45[NT][NCHAIN][2];    // B1's two real dwords

    // ---- init: f0[k] = W0[c][p][k] * gate0[k] (f32, unpacked f16 gates) ----
#pragma unroll
    for (int tile = 0; tile < NT; ++tile) {
        const uint4* rp = (const uint4*)(
            G + ((size_t)dp[0] * NPTS + (n0 + tile * 32 + nl)) * 24 + goff);
        uint4 r0 = rp[0], r1 = rp[1], r2 = rp[2];
        unsigned gw[6] = {r0.x, r0.y, r0.z, r0.w, r1.x, r1.y};
        unsigned sw[6] = {r1.z, r1.w, r2.x, r2.y, r2.z, r2.w};
        float gcf[12], scf[12];
#pragma unroll
        for (int q = 0; q < 6; ++q) {
            fp16x2 gh = u2h(gw[q]), sh = u2h(sw[q]);
            gcf[2 * q] = (float)gh.x; gcf[2 * q + 1] = (float)gh.y;
            scf[2 * q] = (float)sh.x; scf[2 * q + 1] = (float)sh.y;
        }
#pragma unroll
        for (int c = 0; c < NCHAIN; ++c) {
            const float* w0r = W0 + (c * PP + p) * OO;
            float val[12];
#pragma unroll
            for (int r = 0; r < 8; ++r) {
                float ws = hi ? w0r[r + 8] : w0r[r];
                val[r] = ws * (c == 0 ? gcf[r] : scf[r]);
            }
#pragma unroll
            for (int r = 8; r < 12; ++r) {
                float ws = hi ? 0.f : w0r[r + 8];
                val[r] = ws * (c == 0 ? gcf[r] : scf[r]);
            }
#pragma unroll
            for (int e = 0; e < 4; ++e)
                stB0[tile][c][e] = pack_pk(val[2 * e], val[2 * e + 1]);
            s45[tile][c][0] = pack_pk(val[8], val[9]);
            s45[tile][c][1] = pack_pk(val[10], val[11]);
        }
    }

    const float coef[NCHAIN] = {0.f, 1.f, 0.5f, 1.f / 6.f, 1.f / 24.f,
                                1.f / 120.f, 1.f / 720.f};
    float sm[NT], sv[NT];
#pragma unroll
    for (int tile = 0; tile < NT; ++tile) { sm[tile] = 0.f; sv[tile] = 0.f; }

    __syncthreads();   // drains vmcnt → buf0 staged

#pragma unroll
    for (int i = 1; i < DD; ++i) {
        const int cur = (i - 1) & 1;

        // gate loads first (consumed soonest)
        uint4 gr[NT][3];
#pragma unroll
        for (int tile = 0; tile < NT; ++tile) {
            const uint4* rp = (const uint4*)(
                G + ((size_t)dp[i] * NPTS + (n0 + tile * 32 + nl)) * 24 + goff);
            gr[tile][0] = rp[0]; gr[tile][1] = rp[1]; gr[tile][2] = rp[2];
        }

        // issue next step's staging into the other buffer (latency hides
        // under this step's compute; drained by the end-of-step barrier)
        if (i < DD - 1) {
            const _Float16* wbase = WA + (size_t)(i * PP + p) * 1024;  // [c][i][p]
#pragma unroll
            for (int u = wv; u < 2 * NCHAIN; u += 4) {
                int c = u >> 1, h = u & 1;
                const _Float16* src =
                    wbase + (size_t)c * (DD - 1) * PP * 1024 + h * 512 + lane * 8;
                __builtin_amdgcn_global_load_lds(
                    (const AS1 u32*)src, (AS3 u32*)&Alds[cur ^ 1][u * 512], 16, 0, 0);
            }
        }

        unsigned gw[NT][6], sw[NT][6];
#pragma unroll
        for (int tile = 0; tile < NT; ++tile) {
            gw[tile][0] = gr[tile][0].x; gw[tile][1] = gr[tile][0].y;
            gw[tile][2] = gr[tile][0].z; gw[tile][3] = gr[tile][0].w;
            gw[tile][4] = gr[tile][1].x; gw[tile][5] = gr[tile][1].y;
            sw[tile][0] = gr[tile][1].z; sw[tile][1] = gr[tile][1].w;
            sw[tile][2] = gr[tile][2].x; sw[tile][3] = gr[tile][2].y;
            sw[tile][4] = gr[tile][2].z; sw[tile][5] = gr[tile][2].w;
        }

        // final step needs f32 gates for the accurate reduction
        float gcf[NT][12], scf[NT][12];
        if (i == DD - 1) {
#pragma unroll
            for (int tile = 0; tile < NT; ++tile)
#pragma unroll
                for (int q = 0; q < 6; ++q) {
                    fp16x2 gh = u2h(gw[tile][q]), sh = u2h(sw[tile][q]);
                    gcf[tile][2 * q] = (float)gh.x; gcf[tile][2 * q + 1] = (float)gh.y;
                    scf[tile][2 * q] = (float)sh.x; scf[tile][2 * q + 1] = (float)sh.y;
                }
        }

#pragma unroll
        for (int c = 0; c < NCHAIN; ++c) {
            // conflict-free fragment reads: lane*16B contiguous
            const _Float16* ab = &Alds[cur][c * 1024 + lane * 8];
            half8 A0 = *(const half8*)(ab);
            half8 A1 = *(const half8*)(ab + 512);

#pragma unroll
            for (int tile = 0; tile < NT; ++tile) {
                union { uint4v u; half8 h; } B0;
                B0.u = stB0[tile][c];
                union { unsigned u[4]; half8 h; } B1;
                B1.u[0] = s45[tile][c][0]; B1.u[1] = s45[tile][c][1];
                B1.u[2] = uz;              B1.u[3] = uz;  // k>=20: A cols are 0

                floatx16 acc;
                acc = __builtin_amdgcn_mfma_f32_32x32x16_f16(A0, B0.h, kZero, 0, 0, 0);
                acc = __builtin_amdgcn_mfma_f32_32x32x16_f16(A1, B1.h, acc, 0, 0, 0);

                if (i < DD - 1) {
                    // gate+pack in f16, written IN PLACE into the B0/B1 state
#pragma unroll
                    for (int e = 0; e < 4; ++e) {
                        fp16x2 pr = __builtin_amdgcn_cvt_pkrtz(acc[2 * e], acc[2 * e + 1]);
                        fp16x2 gv = u2h(c == 0 ? gw[tile][e] : sw[tile][e]);
                        stB0[tile][c][e] = h2u(pr * gv);
                    }
#pragma unroll
                    for (int e = 4; e < 6; ++e) {
                        fp16x2 pr = __builtin_amdgcn_cvt_pkrtz(acc[2 * e], acc[2 * e + 1]);
                        fp16x2 gv = u2h(c == 0 ? gw[tile][e] : sw[tile][e]);
                        s45[tile][c][e - 4] = h2u(pr * gv);
                    }
                } else {
                    float s = 0.f;
#pragma unroll
                    for (int r = 0; r < 12; ++r)
                        s += acc[r] * (c == 0 ? gcf[tile][r] : scf[tile][r]);
                    if (c == 0) sm[tile] = s;
                    else        sv[tile] += coef[c] * s;
                }
            }
        }

        if (i < DD - 1) __syncthreads();  // staging done + all ds_reads done
    }

    // ---- epilogue: combine half-waves, write per-p partials ----
#pragma unroll
    for (int tile = 0; tile < NT; ++tile) {
        float m = sm[tile] + __shfl_xor(sm[tile], 32, 64);
        float v = sv[tile] + __shfl_xor(sv[tile], 32, 64);
        if (lane < 32) {
            partial[(size_t)p * NPTS + n0 + tile * 32 + nl] = m;
            partial[(size_t)(PP + p) * NPTS + n0 + tile * 32 + nl] = v;
        }
    }
}

// ---------------------------------------------------------------------------
// Reduce over p: out[n][0] = sum_p mean_p[n]; out[n][1] = sum_p var_p[n]
// ---------------------------------------------------------------------------
__global__ void reduce_kernel(const float* __restrict__ partial,
                              float* __restrict__ out) {
    int n = blockIdx.x * 256 + threadIdx.x;
    float m = 0.f, v = 0.f;
#pragma unroll
    for (int p = 0; p < PP; ++p) {
        m += partial[(size_t)p * NPTS + n];
        v += partial[(size_t)(PP + p) * NPTS + n];
    }
    out[2 * n] = m;
    out[2 * n + 1] = v;
}

extern "C" void kernel_launch(void* const* d_in, const int* in_sizes, int n_in,
                              void* d_out, int out_size, void* d_ws, size_t ws_size,
                              hipStream_t stream) {
    const float* X      = (const float*)d_in[0];
    const int*   perm   = (const int*)d_in[1];
    const float* meanw0 = (const float*)d_in[2];
    const float* meanw  = (const float*)d_in[3];
    const float* varw0  = (const float*)d_in[4];
    const float* varw   = (const float*)d_in[5];
    float* out = (float*)d_out;

    // workspace: [W0: 2800 f32 = 11,200B][WA: 1,003,520 f16 = 2,007,040B]
    //            [partial: 2*20*32768 f32 = 5,242,880B]
    //            [G: 8*32768*24 dwords = 25,165,824B]   total 32,426,944B
    float*     W0      = (float*)d_ws;
    _Float16*  WA      = (_Float16*)((char*)d_ws + 11200);
    float*     partial = (float*)((char*)d_ws + 11200 + 2007040);
    unsigned*  G       = (unsigned*)((char*)d_ws + 11200 + 2007040 + 5242880);

    int prep_n = NCHAIN * PP * OO + NCHAIN * (DD - 1) * PP * 32 * 32 + NPTS * DD;
    hipLaunchKernelGGL(prep_kernel, dim3((prep_n + 255) / 256), dim3(256), 0,
                       stream, X, meanw0, meanw, varw0, varw, W0, WA, G);

    dim3 grid(NPTS / (128 * NT), PP);  // 4 waves/block, NT*32 pts/wave
    hipLaunchKernelGGL(chain_kernel, grid, dim3(256), 0, stream,
                       perm, W0, WA, G, partial);

    hipLaunchKernelGGL(reduce_kernel, dim3(NPTS / 256), dim3(256), 0, stream,
                       partial, out);
}

// Round 6
// 156.995 us; speedup vs baseline: 4.9715x; 1.0394x over previous
//
#include <hip/hip_runtime.h>
#include <math.h>

#define NPTS 32768
#define DD 8
#define OO 20      // ORDER+1
#define PP 20
#define NCHAIN 7   // c=0: mean chain; c=1..6: variance moment k=c
#define NT 2       // point-tiles (32 pts each) per wave — amortizes A loads

typedef _Float16 half8 __attribute__((ext_vector_type(8)));
typedef __fp16 fp16x2 __attribute__((ext_vector_type(2)));
typedef float floatx16 __attribute__((ext_vector_type(16)));
typedef unsigned int u32;

#define AS1 __attribute__((address_space(1)))
#define AS3 __attribute__((address_space(3)))

// sigma: row permutation baked into A so that C-layout output == next B layout
// (swap rows 4..7 <-> 8..11; identity elsewhere)
__device__ __forceinline__ int sigma_row(int m) {
    return (m >= 4 && m < 12) ? (m ^ 12) : m;
}

// basis b_q = binom[q] t^q (1-t)^(19-q), fp32 (prep only)
__device__ __forceinline__ void basis20(float tv, float* g) {
    constexpr float binom[OO] = {
        1.f, 19.f, 171.f, 969.f, 3876.f, 11628.f, 27132.f, 50388.f, 75582.f,
        92378.f, 92378.f, 75582.f, 50388.f, 27132.f, 11628.f, 3876.f, 969.f,
        171.f, 19.f, 1.f};
    float a = tv, b = 1.f - tv, v = 1.f;
#pragma unroll
    for (int q = 0; q < OO; ++q) { g[q] = v; v *= a; }
    v = 1.f;
#pragma unroll
    for (int q = OO - 1; q >= 0; --q) { g[q] = g[q] * v * binom[q]; v *= b; }
}

// RTN pack of two f32 into f16x2 dword (prep only — accuracy over speed)
__device__ __forceinline__ unsigned pk2rtn(float a, float b) {
    union { _Float16 h[2]; unsigned u; } cv;
    cv.h[0] = (_Float16)a; cv.h[1] = (_Float16)b;
    return cv.u;
}

__device__ __forceinline__ unsigned pack_pk(float x, float y) {
    union { fp16x2 h; unsigned u; } cv;
    cv.h = __builtin_amdgcn_cvt_pkrtz(x, y);
    return cv.u;
}

__device__ __forceinline__ fp16x2 u2h(unsigned u) {
    union { unsigned u; fp16x2 h; } c; c.u = u; return c.h;
}
__device__ __forceinline__ unsigned h2u(fp16x2 h) {
    union { unsigned u; fp16x2 h; } c; c.h = h; return c.u;
}

// ---------------------------------------------------------------------------
// Prep (one launch, three ranges):
//   W0[c][p][q]  fp32 = c==0 ? exp(meanw0) : exp(2*meanw0 + c*varw0)
//   WA[c][i][p][frag][lane][j] f16 — MFMA A-fragment order:
//     element = Apad[m][k], m = lane&31, k = (lane>>5)*8 + frag*16 + j,
//     Apad[m][k] = (q=sigma(m))<20 && k<20 ? W_c[o=k][q] : 0
//     This makes global_load_lds's linear (lane*16B) LDS write == the exact
//     per-lane ds_read_b128 fragment layout (conflict-free, no swizzle).
//   G[d][n]: 24 dwords (96B) of f16x2 gate records in per-lane layout:
//     dwords  0..5  lo-half gate  pairs: (g0,g1)(g2,g3)(g4,g5)(g6,g7)(g16,g17)(g18,g19)
//     dwords  6..11 lo-half gate² (squared in f32, rounded once)
//     dwords 12..17 hi-half gate  pairs: (g8,g9)..(g14,g15),(0,0),(0,0)
//     dwords 18..23 hi-half gate²
//   NOTE: the G record is composed in NAMED uint4 registers — an earlier
//   version built a local array and stored via ((const uint4*)rec)[q]; that
//   pointer-pun defeated SROA and put 96B/thread in scratch (~35us of
//   scratch traffic on this dispatch).
// ---------------------------------------------------------------------------
__global__ void prep_kernel(const float* __restrict__ X,
                            const float* __restrict__ meanw0,
                            const float* __restrict__ meanw,
                            const float* __restrict__ varw0,
                            const float* __restrict__ varw,
                            float* __restrict__ W0,
                            _Float16* __restrict__ WA,
                            unsigned* __restrict__ G) {
    int e = blockIdx.x * 256 + threadIdx.x;
    const int n0 = NCHAIN * PP * OO;                 // 2800
    const int nW = NCHAIN * (DD - 1) * PP * 32 * 32; // 1,003,520
    const int nG = NPTS * DD;                        // 262,144
    if (e < n0) {
        int q = e % OO;
        int rem = e / OO;
        int p = rem % PP;
        int c = rem / PP;
        float m = meanw0[p * OO + q];
        W0[e] = (c == 0) ? __expf(m) : __expf(2.f * m + (float)c * varw0[p * OO + q]);
    } else if (e < n0 + nW) {
        int idx = e - n0;
        int j = idx & 7; idx >>= 3;
        int l = idx & 63; idx >>= 6;
        int f = idx & 1; idx >>= 1;
        int p = idx % PP; idx /= PP;
        int i = idx % (DD - 1);
        int c = idx / (DD - 1);
        int m = l & 31;
        int k = (l >> 5) * 8 + f * 16 + j;
        int q = sigma_row(m);
        float v = 0.f;
        if (q < OO && k < OO) {
            int mi = ((i * PP + p) * OO + k) * OO + q;   // meanw[i][p][o=k][q']
            float mm = meanw[mi];
            v = (c == 0) ? __expf(mm) : __expf(2.f * mm + (float)c * varw[mi]);
        }
        WA[e - n0] = (_Float16)v;
    } else if (e < n0 + nW + nG) {
        int idx = e - n0 - nW;
        int n = idx & (NPTS - 1);
        int d = idx >> 15;
        float g[OO];
        basis20(X[(size_t)n * DD + d], g);
        float lo[12], hi12[12];
#pragma unroll
        for (int r = 0; r < 8; ++r) lo[r] = g[r];
#pragma unroll
        for (int r = 0; r < 4; ++r) lo[8 + r] = g[16 + r];
#pragma unroll
        for (int r = 0; r < 8; ++r) hi12[r] = g[8 + r];
#pragma unroll
        for (int r = 0; r < 4; ++r) hi12[8 + r] = 0.f;
        // compose the 24 dwords directly in registers (no local array pun)
        uint4 o0, o1, o2, o3, o4, o5;
        o0.x = pk2rtn(lo[0], lo[1]);
        o0.y = pk2rtn(lo[2], lo[3]);
        o0.z = pk2rtn(lo[4], lo[5]);
        o0.w = pk2rtn(lo[6], lo[7]);
        o1.x = pk2rtn(lo[8], lo[9]);
        o1.y = pk2rtn(lo[10], lo[11]);
        o1.z = pk2rtn(lo[0] * lo[0], lo[1] * lo[1]);
        o1.w = pk2rtn(lo[2] * lo[2], lo[3] * lo[3]);
        o2.x = pk2rtn(lo[4] * lo[4], lo[5] * lo[5]);
        o2.y = pk2rtn(lo[6] * lo[6], lo[7] * lo[7]);
        o2.z = pk2rtn(lo[8] * lo[8], lo[9] * lo[9]);
        o2.w = pk2rtn(lo[10] * lo[10], lo[11] * lo[11]);
        o3.x = pk2rtn(hi12[0], hi12[1]);
        o3.y = pk2rtn(hi12[2], hi12[3]);
        o3.z = pk2rtn(hi12[4], hi12[5]);
        o3.w = pk2rtn(hi12[6], hi12[7]);
        o4.x = pk2rtn(hi12[8], hi12[9]);
        o4.y = pk2rtn(hi12[10], hi12[11]);
        o4.z = pk2rtn(hi12[0] * hi12[0], hi12[1] * hi12[1]);
        o4.w = pk2rtn(hi12[2] * hi12[2], hi12[3] * hi12[3]);
        o5.x = pk2rtn(hi12[4] * hi12[4], hi12[5] * hi12[5]);
        o5.y = pk2rtn(hi12[6] * hi12[6], hi12[7] * hi12[7]);
        o5.z = pk2rtn(hi12[8] * hi12[8], hi12[9] * hi12[9]);
        o5.w = pk2rtn(hi12[10] * hi12[10], hi12[11] * hi12[11]);
        uint4* out = (uint4*)(G + (size_t)(d * NPTS + n) * 24);
        out[0] = o0; out[1] = o1; out[2] = o2;
        out[3] = o3; out[4] = o4; out[5] = o5;
    }
}

// ---------------------------------------------------------------------------
// One wave = one p x NT*32 points x all 7 chains. State st[tile][c][0..5] is
// the f16 B-layout activation. Sigma row-permutation of A makes the MFMA C
// output pack DIRECTLY into the same lane's next-step B dwords.
// A-matrices (14KB per i-step, shared by all 4 waves: same p) are staged
// block-wide into double-buffered LDS via global_load_lds, one step ahead;
// the hot loop reads them with conflict-free ds_read_b128 at lane*16.
// NOTE (r4/r5 lessons): live state needs ~120 VGPRs. (256,4) launch_bounds
// caps at 64 VGPR -> total spill (8x). The "persistent uint32x4 B0 operand"
// variant hit 128 VGPR + partial spill (94us vs 87us). This exact structure
// (marshal unions, (256,2)) is the measured optimum — don't touch either.
// ---------------------------------------------------------------------------
__global__ __launch_bounds__(256, 2) void chain_kernel(
    const int* __restrict__ perm,
    const float* __restrict__ W0, const _Float16* __restrict__ WA,
    const unsigned* __restrict__ G, float* __restrict__ partial) {
    const int lane = threadIdx.x & 63;
    const int wv = threadIdx.x >> 6;
    const int nl = lane & 31;
    const bool hi = (lane >> 5) != 0;
    const int n0 = (blockIdx.x * 4 + wv) * (32 * NT);
    const int p = blockIdx.y;
    const int goff = hi ? 12 : 0;

    // [buf][c*1024 + frag*512 + lane*8] halves; 2 x 14336 B
    __shared__ __align__(16) _Float16 Alds[2][NCHAIN * 1024];

    int dp[DD];
#pragma unroll
    for (int i = 0; i < DD; ++i) dp[i] = perm[p * DD + i];

    // opaque zero: perm values are 0..7, so uz == 0, but the compiler can't
    // prove it — kZero stays pinned instead of being re-emitted per MFMA.
    const unsigned uz = ((unsigned)dp[0]) >> 20;
    const float fz = __uint_as_float(uz);
    floatx16 kZero;
#pragma unroll
    for (int r = 0; r < 16; ++r) kZero[r] = fz;

    // ---- issue staging of i=1 A-matrices into buf0 (latency hidden by init)
    {
        const _Float16* wbase = WA + (size_t)p * 1024;  // [c][i=0][p]
#pragma unroll
        for (int u = wv; u < 2 * NCHAIN; u += 4) {
            int c = u >> 1, h = u & 1;
            const _Float16* src =
                wbase + (size_t)c * (DD - 1) * PP * 1024 + h * 512 + lane * 8;
            __builtin_amdgcn_global_load_lds(
                (const AS1 u32*)src, (AS3 u32*)&Alds[0][u * 512], 16, 0, 0);
        }
    }

    unsigned st[NT][NCHAIN][6];

    // ---- init: f0[k] = W0[c][p][k] * gate0[k] (f32, unpacked f16 gates) ----
#pragma unroll
    for (int tile = 0; tile < NT; ++tile) {
        const uint4* rp = (const uint4*)(
            G + ((size_t)dp[0] * NPTS + (n0 + tile * 32 + nl)) * 24 + goff);
        uint4 r0 = rp[0], r1 = rp[1], r2 = rp[2];
        unsigned gw[6] = {r0.x, r0.y, r0.z, r0.w, r1.x, r1.y};
        unsigned sw[6] = {r1.z, r1.w, r2.x, r2.y, r2.z, r2.w};
        float gcf[12], scf[12];
#pragma unroll
        for (int q = 0; q < 6; ++q) {
            fp16x2 gh = u2h(gw[q]), sh = u2h(sw[q]);
            gcf[2 * q] = (float)gh.x; gcf[2 * q + 1] = (float)gh.y;
            scf[2 * q] = (float)sh.x; scf[2 * q + 1] = (float)sh.y;
        }
#pragma unroll
        for (int c = 0; c < NCHAIN; ++c) {
            const float* w0r = W0 + (c * PP + p) * OO;
            float val[12];
#pragma unroll
            for (int r = 0; r < 8; ++r) {
                float ws = hi ? w0r[r + 8] : w0r[r];
                val[r] = ws * (c == 0 ? gcf[r] : scf[r]);
            }
#pragma unroll
            for (int r = 8; r < 12; ++r) {
                float ws = hi ? 0.f : w0r[r + 8];
                val[r] = ws * (c == 0 ? gcf[r] : scf[r]);
            }
#pragma unroll
            for (int e = 0; e < 6; ++e)
                st[tile][c][e] = pack_pk(val[2 * e], val[2 * e + 1]);
        }
    }

    const float coef[NCHAIN] = {0.f, 1.f, 0.5f, 1.f / 6.f, 1.f / 24.f,
                                1.f / 120.f, 1.f / 720.f};
    float sm[NT], sv[NT];
#pragma unroll
    for (int tile = 0; tile < NT; ++tile) { sm[tile] = 0.f; sv[tile] = 0.f; }

    __syncthreads();   // drains vmcnt → buf0 staged

#pragma unroll
    for (int i = 1; i < DD; ++i) {
        const int cur = (i - 1) & 1;

        // issue next step's staging into the other buffer (latency hides
        // under this step's compute; drained by the end-of-step barrier)
        if (i < DD - 1) {
            const _Float16* wbase = WA + (size_t)(i * PP + p) * 1024;  // [c][i][p]
#pragma unroll
            for (int u = wv; u < 2 * NCHAIN; u += 4) {
                int c = u >> 1, h = u & 1;
                const _Float16* src =
                    wbase + (size_t)c * (DD - 1) * PP * 1024 + h * 512 + lane * 8;
                __builtin_amdgcn_global_load_lds(
                    (const AS1 u32*)src, (AS3 u32*)&Alds[cur ^ 1][u * 512], 16, 0, 0);
            }
        }

        unsigned gw[NT][6], sw[NT][6];
#pragma unroll
        for (int tile = 0; tile < NT; ++tile) {
            const uint4* rp = (const uint4*)(
                G + ((size_t)dp[i] * NPTS + (n0 + tile * 32 + nl)) * 24 + goff);
            uint4 r0 = rp[0], r1 = rp[1], r2 = rp[2];
            gw[tile][0] = r0.x; gw[tile][1] = r0.y; gw[tile][2] = r0.z;
            gw[tile][3] = r0.w; gw[tile][4] = r1.x; gw[tile][5] = r1.y;
            sw[tile][0] = r1.z; sw[tile][1] = r1.w; sw[tile][2] = r2.x;
            sw[tile][3] = r2.y; sw[tile][4] = r2.z; sw[tile][5] = r2.w;
        }

        // final step needs f32 gates for the accurate reduction
        float gcf[NT][12], scf[NT][12];
        if (i == DD - 1) {
#pragma unroll
            for (int tile = 0; tile < NT; ++tile)
#pragma unroll
                for (int q = 0; q < 6; ++q) {
                    fp16x2 gh = u2h(gw[tile][q]), sh = u2h(sw[tile][q]);
                    gcf[tile][2 * q] = (float)gh.x; gcf[tile][2 * q + 1] = (float)gh.y;
                    scf[tile][2 * q] = (float)sh.x; scf[tile][2 * q + 1] = (float)sh.y;
                }
        }

#pragma unroll
        for (int c = 0; c < NCHAIN; ++c) {
            // conflict-free fragment reads: lane*16B contiguous
            const _Float16* ab = &Alds[cur][c * 1024 + lane * 8];
            half8 A0 = *(const half8*)(ab);
            half8 A1 = *(const half8*)(ab + 512);

#pragma unroll
            for (int tile = 0; tile < NT; ++tile) {
                union { unsigned u[4]; half8 h; } B0, B1;
                B0.u[0] = st[tile][c][0]; B0.u[1] = st[tile][c][1];
                B0.u[2] = st[tile][c][2]; B0.u[3] = st[tile][c][3];
                B1.u[0] = st[tile][c][4]; B1.u[1] = st[tile][c][5];
                B1.u[2] = uz;             B1.u[3] = uz;  // k>=20: A cols are 0

                floatx16 acc;
                acc = __builtin_amdgcn_mfma_f32_32x32x16_f16(A0, B0.h, kZero, 0, 0, 0);
                acc = __builtin_amdgcn_mfma_f32_32x32x16_f16(A1, B1.h, acc, 0, 0, 0);

                if (i < DD - 1) {
                    // gate+pack in f16: 6 cvt_pkrtz + 6 v_pk_mul_f16
#pragma unroll
                    for (int e = 0; e < 6; ++e) {
                        fp16x2 pr = __builtin_amdgcn_cvt_pkrtz(acc[2 * e], acc[2 * e + 1]);
                        fp16x2 gv = u2h(c == 0 ? gw[tile][e] : sw[tile][e]);
                        st[tile][c][e] = h2u(pr * gv);
                    }
                } else {
                    float s = 0.f;
#pragma unroll
                    for (int r = 0; r < 12; ++r)
                        s += acc[r] * (c == 0 ? gcf[tile][r] : scf[tile][r]);
                    if (c == 0) sm[tile] = s;
                    else        sv[tile] += coef[c] * s;
                }
            }
        }

        if (i < DD - 1) __syncthreads();  // staging done + all ds_reads done
    }

    // ---- epilogue: combine half-waves, write per-p partials ----
#pragma unroll
    for (int tile = 0; tile < NT; ++tile) {
        float m = sm[tile] + __shfl_xor(sm[tile], 32, 64);
        float v = sv[tile] + __shfl_xor(sv[tile], 32, 64);
        if (lane < 32) {
            partial[(size_t)p * NPTS + n0 + tile * 32 + nl] = m;
            partial[(size_t)(PP + p) * NPTS + n0 + tile * 32 + nl] = v;
        }
    }
}

// ---------------------------------------------------------------------------
// Reduce over p: out[n][0] = sum_p mean_p[n]; out[n][1] = sum_p var_p[n]
// ---------------------------------------------------------------------------
__global__ void reduce_kernel(const float* __restrict__ partial,
                              float* __restrict__ out) {
    int n = blockIdx.x * 256 + threadIdx.x;
    float m = 0.f, v = 0.f;
#pragma unroll
    for (int p = 0; p < PP; ++p) {
        m += partial[(size_t)p * NPTS + n];
        v += partial[(size_t)(PP + p) * NPTS + n];
    }
    out[2 * n] = m;
    out[2 * n + 1] = v;
}

extern "C" void kernel_launch(void* const* d_in, const int* in_sizes, int n_in,
                              void* d_out, int out_size, void* d_ws, size_t ws_size,
                              hipStream_t stream) {
    const float* X      = (const float*)d_in[0];
    const int*   perm   = (const int*)d_in[1];
    const float* meanw0 = (const float*)d_in[2];
    const float* meanw  = (const float*)d_in[3];
    const float* varw0  = (const float*)d_in[4];
    const float* varw   = (const float*)d_in[5];
    float* out = (float*)d_out;

    // workspace: [W0: 2800 f32 = 11,200B][WA: 1,003,520 f16 = 2,007,040B]
    //            [partial: 2*20*32768 f32 = 5,242,880B]
    //            [G: 8*32768*24 dwords = 25,165,824B]   total 32,426,944B
    float*     W0      = (float*)d_ws;
    _Float16*  WA      = (_Float16*)((char*)d_ws + 11200);
    float*     partial = (float*)((char*)d_ws + 11200 + 2007040);
    unsigned*  G       = (unsigned*)((char*)d_ws + 11200 + 2007040 + 5242880);

    int prep_n = NCHAIN * PP * OO + NCHAIN * (DD - 1) * PP * 32 * 32 + NPTS * DD;
    hipLaunchKernelGGL(prep_kernel, dim3((prep_n + 255) / 256), dim3(256), 0,
                       stream, X, meanw0, meanw, varw0, varw, W0, WA, G);

    dim3 grid(NPTS / (128 * NT), PP);  // 4 waves/block, NT*32 pts/wave
    hipLaunchKernelGGL(chain_kernel, grid, dim3(256), 0, stream,
                       perm, W0, WA, G, partial);

    hipLaunchKernelGGL(reduce_kernel, dim3(NPTS / 256), dim3(256), 0, stream,
                       partial, out);
}

// Round 9
// 143.389 us; speedup vs baseline: 5.4432x; 1.0949x over previous
//
#include <hip/hip_runtime.h>
#include <math.h>

#define NPTS 32768
#define DD 8
#define OO 20      // ORDER+1
#define PP 20
#define NCHAIN 7   // c=0: mean chain; c=1..6: variance moment k=c
#define NT 2       // point-tiles (32 pts each) per wave — amortizes A loads

typedef _Float16 half8 __attribute__((ext_vector_type(8)));
typedef __fp16 fp16x2 __attribute__((ext_vector_type(2)));
typedef float floatx16 __attribute__((ext_vector_type(16)));
typedef unsigned int u32;

#define AS1 __attribute__((address_space(1)))
#define AS3 __attribute__((address_space(3)))

// sigma: row permutation baked into A so that C-layout output == next B layout
// (swap rows 4..7 <-> 8..11; identity elsewhere)
__device__ __forceinline__ int sigma_row(int m) {
    return (m >= 4 && m < 12) ? (m ^ 12) : m;
}

// basis b_q = binom[q] t^q (1-t)^(19-q), fp32 (prep only)
__device__ __forceinline__ void basis20(float tv, float* g) {
    constexpr float binom[OO] = {
        1.f, 19.f, 171.f, 969.f, 3876.f, 11628.f, 27132.f, 50388.f, 75582.f,
        92378.f, 92378.f, 75582.f, 50388.f, 27132.f, 11628.f, 3876.f, 969.f,
        171.f, 19.f, 1.f};
    float a = tv, b = 1.f - tv, v = 1.f;
#pragma unroll
    for (int q = 0; q < OO; ++q) { g[q] = v; v *= a; }
    v = 1.f;
#pragma unroll
    for (int q = OO - 1; q >= 0; --q) { g[q] = g[q] * v * binom[q]; v *= b; }
}

// RTN pack of two f32 into f16x2 dword (prep only — accuracy over speed)
__device__ __forceinline__ unsigned pk2rtn(float a, float b) {
    union { _Float16 h[2]; unsigned u; } cv;
    cv.h[0] = (_Float16)a; cv.h[1] = (_Float16)b;
    return cv.u;
}

__device__ __forceinline__ unsigned pack_pk(float x, float y) {
    union { fp16x2 h; unsigned u; } cv;
    cv.h = __builtin_amdgcn_cvt_pkrtz(x, y);
    return cv.u;
}

__device__ __forceinline__ fp16x2 u2h(unsigned u) {
    union { unsigned u; fp16x2 h; } c; c.u = u; return c.h;
}
__device__ __forceinline__ unsigned h2u(fp16x2 h) {
    union { unsigned u; fp16x2 h; } c; c.h = h; return c.u;
}

// ---------------------------------------------------------------------------
// Zero the output buffer (graph-capture-safe replacement for hipMemsetAsync).
// 2*NPTS floats = 65536 f32 = 16384 float4 stores.
// ---------------------------------------------------------------------------
__global__ void zero_kernel(float4* __restrict__ out) {
    int e = blockIdx.x * 256 + threadIdx.x;
    out[e] = make_float4(0.f, 0.f, 0.f, 0.f);
}

// ---------------------------------------------------------------------------
// Prep (one launch, three ranges):
//   W0[c][p][q]  fp32 = c==0 ? exp(meanw0) : exp(2*meanw0 + c*varw0)
//   WA[c][i][p][frag][lane][j] f16 — MFMA A-fragment order:
//     element = Apad[m][k], m = lane&31, k = (lane>>5)*8 + frag*16 + j,
//     Apad[m][k] = (q=sigma(m))<20 && k<20 ? W_c[o=k][q] : 0
//     This makes global_load_lds's linear (lane*16B) LDS write == the exact
//     per-lane ds_read_b128 fragment layout (conflict-free, no swizzle).
//   G[d][n]: 12 dwords (48B) of f16x2 GATE records in per-lane layout
//     (gate^2 is computed on the fly in the chain kernel — ws size is paid
//      every harness iteration as re-poison fill, so G stores gates only):
//     dwords 0..5  lo-half pairs: (g0,g1)(g2,g3)(g4,g5)(g6,g7)(g16,g17)(g18,g19)
//     dwords 6..11 hi-half pairs: (g8,g9)(g10,g11)(g12,g13)(g14,g15)(0,0)(0,0)
// ---------------------------------------------------------------------------
__global__ void prep_kernel(const float* __restrict__ X,
                            const float* __restrict__ meanw0,
                            const float* __restrict__ meanw,
                            const float* __restrict__ varw0,
                            const float* __restrict__ varw,
                            float* __restrict__ W0,
                            _Float16* __restrict__ WA,
                            unsigned* __restrict__ G) {
    int e = blockIdx.x * 256 + threadIdx.x;
    const int n0 = NCHAIN * PP * OO;                 // 2800
    const int nW = NCHAIN * (DD - 1) * PP * 32 * 32; // 1,003,520
    const int nG = NPTS * DD;                        // 262,144
    if (e < n0) {
        int q = e % OO;
        int rem = e / OO;
        int p = rem % PP;
        int c = rem / PP;
        float m = meanw0[p * OO + q];
        W0[e] = (c == 0) ? __expf(m) : __expf(2.f * m + (float)c * varw0[p * OO + q]);
    } else if (e < n0 + nW) {
        int idx = e - n0;
        int j = idx & 7; idx >>= 3;
        int l = idx & 63; idx >>= 6;
        int f = idx & 1; idx >>= 1;
        int p = idx % PP; idx /= PP;
        int i = idx % (DD - 1);
        int c = idx / (DD - 1);
        int m = l & 31;
        int k = (l >> 5) * 8 + f * 16 + j;
        int q = sigma_row(m);
        float v = 0.f;
        if (q < OO && k < OO) {
            int mi = ((i * PP + p) * OO + k) * OO + q;   // meanw[i][p][o=k][q']
            float mm = meanw[mi];
            v = (c == 0) ? __expf(mm) : __expf(2.f * mm + (float)c * varw[mi]);
        }
        WA[e - n0] = (_Float16)v;
    } else if (e < n0 + nW + nG) {
        int idx = e - n0 - nW;
        int n = idx & (NPTS - 1);
        int d = idx >> 15;
        float g[OO];
        basis20(X[(size_t)n * DD + d], g);
        // compose the 12 dwords directly in named registers (no array pun)
        uint4 o0, o1, o2;
        o0.x = pk2rtn(g[0], g[1]);
        o0.y = pk2rtn(g[2], g[3]);
        o0.z = pk2rtn(g[4], g[5]);
        o0.w = pk2rtn(g[6], g[7]);
        o1.x = pk2rtn(g[16], g[17]);
        o1.y = pk2rtn(g[18], g[19]);
        o1.z = pk2rtn(g[8], g[9]);
        o1.w = pk2rtn(g[10], g[11]);
        o2.x = pk2rtn(g[12], g[13]);
        o2.y = pk2rtn(g[14], g[15]);
        o2.z = 0u;
        o2.w = 0u;
        uint4* out = (uint4*)(G + (size_t)(d * NPTS + n) * 12);
        out[0] = o0; out[1] = o1; out[2] = o2;
    }
}

// ---------------------------------------------------------------------------
// One wave = one p x NT*32 points x all 7 chains. State st[tile][c][0..5] is
// the f16 B-layout activation. Sigma row-permutation of A makes the MFMA C
// output pack DIRECTLY into the same lane's next-step B dwords.
// A-matrices (14KB per i-step, shared by all 4 waves: same p) are staged
// block-wide into double-buffered LDS via global_load_lds, one step ahead;
// the hot loop reads them with conflict-free ds_read_b128 at lane*16.
// Epilogue atomicAdds per-p results straight into out (out is zeroed by
// zero_kernel) — no partial buffer, no reduce kernel.
// NOTE (r4/r5 lessons): live state needs ~120 VGPRs. (256,4) launch_bounds
// caps at 64 VGPR -> total spill (8x). The "persistent uint32x4 B0 operand"
// variant hit 128 VGPR + partial spill (94us vs 87us). This structure
// (marshal unions, (256,2)) is the measured optimum — don't touch either.
// ---------------------------------------------------------------------------
__global__ __launch_bounds__(256, 2) void chain_kernel(
    const int* __restrict__ perm,
    const float* __restrict__ W0, const _Float16* __restrict__ WA,
    const unsigned* __restrict__ G, float* __restrict__ out) {
    const int lane = threadIdx.x & 63;
    const int wv = threadIdx.x >> 6;
    const int nl = lane & 31;
    const bool hi = (lane >> 5) != 0;
    const int n0 = (blockIdx.x * 4 + wv) * (32 * NT);
    const int p = blockIdx.y;
    const int goffd = hi ? 6 : 0;   // dword offset of this half-lane's gates

    // [buf][c*1024 + frag*512 + lane*8] halves; 2 x 14336 B
    __shared__ __align__(16) _Float16 Alds[2][NCHAIN * 1024];

    int dp[DD];
#pragma unroll
    for (int i = 0; i < DD; ++i) dp[i] = perm[p * DD + i];

    // opaque zero: perm values are 0..7, so uz == 0, but the compiler can't
    // prove it — kZero stays pinned instead of being re-emitted per MFMA.
    const unsigned uz = ((unsigned)dp[0]) >> 20;
    const float fz = __uint_as_float(uz);
    floatx16 kZero;
#pragma unroll
    for (int r = 0; r < 16; ++r) kZero[r] = fz;

    // ---- issue staging of i=1 A-matrices into buf0 (latency hidden by init)
    {
        const _Float16* wbase = WA + (size_t)p * 1024;  // [c][i=0][p]
#pragma unroll
        for (int u = wv; u < 2 * NCHAIN; u += 4) {
            int c = u >> 1, h = u & 1;
            const _Float16* src =
                wbase + (size_t)c * (DD - 1) * PP * 1024 + h * 512 + lane * 8;
            __builtin_amdgcn_global_load_lds(
                (const AS1 u32*)src, (AS3 u32*)&Alds[0][u * 512], 16, 0, 0);
        }
    }

    unsigned st[NT][NCHAIN][6];

    // ---- init: f0[k] = W0[c][p][k] * gate0[k] (f32, unpacked f16 gates) ----
#pragma unroll
    for (int tile = 0; tile < NT; ++tile) {
        const uint2* rp = (const uint2*)(
            G + ((size_t)dp[0] * NPTS + (n0 + tile * 32 + nl)) * 12 + goffd);
        uint2 r0 = rp[0], r1 = rp[1], r2 = rp[2];
        unsigned gw[6] = {r0.x, r0.y, r1.x, r1.y, r2.x, r2.y};
        float gcf[12], scf[12];
#pragma unroll
        for (int q = 0; q < 6; ++q) {
            fp16x2 gh = u2h(gw[q]);
            gcf[2 * q] = (float)gh.x; gcf[2 * q + 1] = (float)gh.y;
        }
#pragma unroll
        for (int r = 0; r < 12; ++r) scf[r] = gcf[r] * gcf[r];
#pragma unroll
        for (int c = 0; c < NCHAIN; ++c) {
            const float* w0r = W0 + (c * PP + p) * OO;
            float val[12];
#pragma unroll
            for (int r = 0; r < 8; ++r) {
                float ws = hi ? w0r[r + 8] : w0r[r];
                val[r] = ws * (c == 0 ? gcf[r] : scf[r]);
            }
#pragma unroll
            for (int r = 8; r < 12; ++r) {
                float ws = hi ? 0.f : w0r[r + 8];
                val[r] = ws * (c == 0 ? gcf[r] : scf[r]);
            }
#pragma unroll
            for (int e = 0; e < 6; ++e)
                st[tile][c][e] = pack_pk(val[2 * e], val[2 * e + 1]);
        }
    }

    const float coef[NCHAIN] = {0.f, 1.f, 0.5f, 1.f / 6.f, 1.f / 24.f,
                                1.f / 120.f, 1.f / 720.f};
    float sm[NT], sv[NT];
#pragma unroll
    for (int tile = 0; tile < NT; ++tile) { sm[tile] = 0.f; sv[tile] = 0.f; }

    __syncthreads();   // drains vmcnt → buf0 staged

#pragma unroll
    for (int i = 1; i < DD; ++i) {
        const int cur = (i - 1) & 1;

        // issue next step's staging into the other buffer (latency hides
        // under this step's compute; drained by the end-of-step barrier)
        if (i < DD - 1) {
            const _Float16* wbase = WA + (size_t)(i * PP + p) * 1024;  // [c][i][p]
#pragma unroll
            for (int u = wv; u < 2 * NCHAIN; u += 4) {
                int c = u >> 1, h = u & 1;
                const _Float16* src =
                    wbase + (size_t)c * (DD - 1) * PP * 1024 + h * 512 + lane * 8;
                __builtin_amdgcn_global_load_lds(
                    (const AS1 u32*)src, (AS3 u32*)&Alds[cur ^ 1][u * 512], 16, 0, 0);
            }
        }

        unsigned gw[NT][6], sw[NT][6];
#pragma unroll
        for (int tile = 0; tile < NT; ++tile) {
            const uint2* rp = (const uint2*)(
                G + ((size_t)dp[i] * NPTS + (n0 + tile * 32 + nl)) * 12 + goffd);
            uint2 r0 = rp[0], r1 = rp[1], r2 = rp[2];
            gw[tile][0] = r0.x; gw[tile][1] = r0.y;
            gw[tile][2] = r1.x; gw[tile][3] = r1.y;
            gw[tile][4] = r2.x; gw[tile][5] = r2.y;
        }
        if (i < DD - 1) {
            // gate^2 in f16 (pad dwords are 0 -> square stays 0)
#pragma unroll
            for (int tile = 0; tile < NT; ++tile)
#pragma unroll
                for (int e = 0; e < 6; ++e) {
                    fp16x2 gh = u2h(gw[tile][e]);
                    sw[tile][e] = h2u(gh * gh);
                }
        }

        // final step needs f32 gates for the accurate reduction
        float gcf[NT][12], scf[NT][12];
        if (i == DD - 1) {
#pragma unroll
            for (int tile = 0; tile < NT; ++tile) {
#pragma unroll
                for (int q = 0; q < 6; ++q) {
                    fp16x2 gh = u2h(gw[tile][q]);
                    gcf[tile][2 * q] = (float)gh.x; gcf[tile][2 * q + 1] = (float)gh.y;
                }
#pragma unroll
                for (int r = 0; r < 12; ++r)
                    scf[tile][r] = gcf[tile][r] * gcf[tile][r];
            }
        }

#pragma unroll
        for (int c = 0; c < NCHAIN; ++c) {
            // conflict-free fragment reads: lane*16B contiguous
            const _Float16* ab = &Alds[cur][c * 1024 + lane * 8];
            half8 A0 = *(const half8*)(ab);
            half8 A1 = *(const half8*)(ab + 512);

#pragma unroll
            for (int tile = 0; tile < NT; ++tile) {
                union { unsigned u[4]; half8 h; } B0, B1;
                B0.u[0] = st[tile][c][0]; B0.u[1] = st[tile][c][1];
                B0.u[2] = st[tile][c][2]; B0.u[3] = st[tile][c][3];
                B1.u[0] = st[tile][c][4]; B1.u[1] = st[tile][c][5];
                B1.u[2] = uz;             B1.u[3] = uz;  // k>=20: A cols are 0

                floatx16 acc;
                acc = __builtin_amdgcn_mfma_f32_32x32x16_f16(A0, B0.h, kZero, 0, 0, 0);
                acc = __builtin_amdgcn_mfma_f32_32x32x16_f16(A1, B1.h, acc, 0, 0, 0);

                if (i < DD - 1) {
                    // gate+pack in f16: 6 cvt_pkrtz + 6 v_pk_mul_f16
#pragma unroll
                    for (int e = 0; e < 6; ++e) {
                        fp16x2 pr = __builtin_amdgcn_cvt_pkrtz(acc[2 * e], acc[2 * e + 1]);
                        fp16x2 gv = u2h(c == 0 ? gw[tile][e] : sw[tile][e]);
                        st[tile][c][e] = h2u(pr * gv);
                    }
                } else {
                    float s = 0.f;
#pragma unroll
                    for (int r = 0; r < 12; ++r)
                        s += acc[r] * (c == 0 ? gcf[tile][r] : scf[tile][r]);
                    if (c == 0) sm[tile] = s;
                    else        sv[tile] += coef[c] * s;
                }
            }
        }

        if (i < DD - 1) __syncthreads();  // staging done + all ds_reads done
    }

    // ---- epilogue: combine half-waves, accumulate into out over p ----
#pragma unroll
    for (int tile = 0; tile < NT; ++tile) {
        float m = sm[tile] + __shfl_xor(sm[tile], 32, 64);
        float v = sv[tile] + __shfl_xor(sv[tile], 32, 64);
        if (lane < 32) {
            int n = n0 + tile * 32 + nl;
            atomicAdd(&out[2 * n], m);
            atomicAdd(&out[2 * n + 1], v);
        }
    }
}

extern "C" void kernel_launch(void* const* d_in, const int* in_sizes, int n_in,
                              void* d_out, int out_size, void* d_ws, size_t ws_size,
                              hipStream_t stream) {
    const float* X      = (const float*)d_in[0];
    const int*   perm   = (const int*)d_in[1];
    const float* meanw0 = (const float*)d_in[2];
    const float* meanw  = (const float*)d_in[3];
    const float* varw0  = (const float*)d_in[4];
    const float* varw   = (const float*)d_in[5];
    float* out = (float*)d_out;

    // workspace: [W0: 2800 f32 = 11,200B][WA: 1,003,520 f16 = 2,007,040B]
    //            [G: 8*32768*12 dwords = 12,582,912B]   total 14,601,152B
    // (ws bytes are re-poisoned by the harness every iteration —
    //  keep this buffer MINIMAL; theory: shrinking ws 32.4->14.6MB ~ -25us)
    float*     W0 = (float*)d_ws;
    _Float16*  WA = (_Float16*)((char*)d_ws + 11200);
    unsigned*  G  = (unsigned*)((char*)d_ws + 11200 + 2007040);

    int prep_n = NCHAIN * PP * OO + NCHAIN * (DD - 1) * PP * 32 * 32 + NPTS * DD;
    hipLaunchKernelGGL(prep_kernel, dim3((prep_n + 255) / 256), dim3(256), 0,
                       stream, X, meanw0, meanw, varw0, varw, W0, WA, G);

    // zero the output (graph-capture-safe; chain atomically accumulates)
    hipLaunchKernelGGL(zero_kernel, dim3(2 * NPTS / (4 * 256)), dim3(256), 0,
                       stream, (float4*)out);

    dim3 grid(NPTS / (128 * NT), PP);  // 4 waves/block, NT*32 pts/wave
    hipLaunchKernelGGL(chain_kernel, grid, dim3(256), 0, stream,
                       perm, W0, WA, G, out);
}